// Round 5
// baseline (430.293 us; speedup 1.0000x reference)
//
#include <hip/hip_runtime.h>
#include <hip/hip_bf16.h>
#include <stdint.h>
#include <type_traits>

// Problem constants (reference: N=16384, F=1024, B=512)
#define N_ROWS 16384
#define F_DIM  1024
#define B_DIM  512
#define K_DIM  1536   // F + B
#define G_DIM  4096   // 4*F
#define NT     24     // K_DIM / 64 K-tiles
#define CB_STR 68     // padded fp32 stride for epilogue LDS tile

typedef __bf16 v8bf __attribute__((ext_vector_type(8)));
typedef float  v4f  __attribute__((ext_vector_type(4)));

typedef const void __attribute__((address_space(1)))* gptr1;
typedef void       __attribute__((address_space(3)))* lptr3;

__device__ __forceinline__ unsigned short f2bf(float x) {
    union { float f; unsigned int u; } c; c.f = x;
    unsigned int u = c.u;
    return (unsigned short)((u + 0x7FFFu + ((u >> 16) & 1u)) >> 16);  // RNE; inputs finite
}

__device__ __forceinline__ float sigmoidf_fast(float x) {
    return 1.f / (1.f + __expf(-x));
}
__device__ __forceinline__ float tanhf_fast(float x) {
    return 1.f - 2.f / (__expf(2.f * x) + 1.f);   // saturates correctly at +/-1
}

// ---------------------------------------------------------------------------
// Merged pack kernel:
//   blocks [0, N_ROWS)           : A = bf16([h_prev | behavior]) row-major
//   blocks [N_ROWS, N_ROWS+G_DIM): W' = bf16 gate-interleaved [Wh | Wx], b'
// ---------------------------------------------------------------------------
__global__ void pack_all(const float* __restrict__ behavior,
                         const float* __restrict__ h_prev,
                         const float* __restrict__ Wh,
                         const float* __restrict__ Wx,
                         const float* __restrict__ b,
                         unsigned short* __restrict__ A,
                         unsigned short* __restrict__ W,
                         float* __restrict__ bperm) {
    const int blk = blockIdx.x;
    const int col = threadIdx.x * 8;              // 0..1528, never straddles 1024
    const float* src;
    unsigned short* dst;
    if (blk < N_ROWS) {
        src = (col < F_DIM) ? h_prev + (long)blk * F_DIM + col
                            : behavior + (long)blk * B_DIM + (col - F_DIM);
        dst = A + (long)blk * K_DIM + col;
    } else {
        const int gp   = blk - N_ROWS;
        const int gate = gp & 3;
        const int f    = gp >> 2;
        const int g    = gate * F_DIM + f;        // original row in Wh/Wx
        src = (col < F_DIM) ? Wh + (long)g * F_DIM + col
                            : Wx + (long)g * B_DIM + (col - F_DIM);
        dst = W + (long)gp * K_DIM + col;
        if (threadIdx.x == 0) bperm[gp] = b[g];
    }
    float4 lo = *(const float4*)src;
    float4 hi = *(const float4*)(src + 4);
    union { unsigned short u[8]; int4 v; } p;
    p.u[0] = f2bf(lo.x); p.u[1] = f2bf(lo.y); p.u[2] = f2bf(lo.z); p.u[3] = f2bf(lo.w);
    p.u[4] = f2bf(hi.x); p.u[5] = f2bf(hi.y); p.u[6] = f2bf(hi.z); p.u[7] = f2bf(hi.w);
    *(int4*)dst = p.v;
}

// ---------------------------------------------------------------------------
// Fused GEMM (gates = A @ W'^T) + bias + activations + c/h epilogue.
// 256x256 tile, BK=64, 8 waves (2Mx4N), 512 threads.
//
// QUADRANT-PER-PHASE schedule (the m201 property the previous ports missed):
// phase q computes output quadrant mt in {2q,2q+1} x all nt over FULL K=64
// (16 MFMA). B fragments are read once at ph0 and held in regs. Hence tile
// t+1's LDS needs arrive staggered: ph0 needs B.all + A.u0,u2; ph2 needs
// A.u1,u3 -- enabling a real counted-vmcnt pipeline (no drain in main loop):
//   issue for t+1 during t: ph0: B.u0,u1 | ph1: B.u2,u3 | ph2: A.u0,u2
//                           | ph3: A.u1,u3
//   waits: vmcnt(2) at t.ph3 (retires B.all+A.u0,u2, issued 1.5-3.5 phases
//   earlier); vmcnt(4) at (t+1).ph1 (retires A.u1,u3, 4 newer stay in
//   flight). Last tile peels with vmcnt(0) at its ph1.
//
// LDS layout (128 KiB, measured conflict-free + 8x128B-coalesced staging):
// A[2 buf][256 rows][128B] at 0, B same at +64KiB; 16B slot s of row r holds
// k-chunk s ^ (r&7); staging lane l covers row l>>3, chunk (l&7)^(l>>3)
// (permutation in global source, LDS dest linear); fragment read offset
// row*128 + (((kh*4+quad) ^ (lrow&7))<<4).
// ---------------------------------------------------------------------------
__global__ __launch_bounds__(512, 2) void lstm_gemm(
    const unsigned short* __restrict__ A,   // [N_ROWS][K_DIM] bf16
    const unsigned short* __restrict__ W,   // [G_DIM][K_DIM]  bf16, interleaved
    const float* __restrict__ bperm,        // [G_DIM]
    const float* __restrict__ c_prev,      // [N_ROWS][F_DIM]
    float* __restrict__ out)                // [N_ROWS][F_DIM]
{
    extern __shared__ char smem[];          // 131072 bytes

    // Plain raster, n fastest (r4-measured: FETCH 254 MB, lowest traffic).
    const int bid = blockIdx.x;                   // 0..1023
    const int n0  = (bid & 15) << 8;              // gate-block * 256
    const int m0  = (bid >> 4) << 8;              // row-block * 256

    const int tid  = threadIdx.x;
    const int lane = tid & 63;
    const int wave = tid >> 6;
    const int wmi  = wave >> 2;                   // 0..1
    const int wni  = wave & 3;                    // 0..3
    const int lrow = lane & 15;
    const int quad = lane >> 4;

    // fragment-read per-lane constants
    const int g7  = lrow & 7;
    const int cs0 = (quad ^ g7) << 4;             // kh0 slot offset (bytes)
    const int cs1 = ((4 + quad) ^ g7) << 4;       // kh1 slot offset
    const int aRd = wmi * 16384 + lrow * 128;     // + buf*32768 + mt*2048 + cs
    const int bRd = wni * 8192  + lrow * 128;     // + 65536 + buf*32768 + nt*2048 + cs

    // staging per-lane source bases: row l>>3, chunk (l&7)^(l>>3)
    const int srow = lane >> 3;
    const int schk = (lane & 7) ^ srow;
    const unsigned short* sA = A + (long)(m0 + wave * 8 + srow) * K_DIM + schk * 8;
    const unsigned short* sB = W + (long)(n0 + wave * 8 + srow) * K_DIM + schk * 8;
    const int sDst = wave * 1024;                 // + matrix base + buf*32768 + u*8192

    v4f acc[8][4] = {};                           // 128 fp32 accum / lane

    // stage one 64-row unit (1 global_load_lds per thread)
    auto stage1 = [&](const unsigned short* src, int ldsbase, int u, int koff) {
        __builtin_amdgcn_global_load_lds(
            (gptr1)(src + (long)u * 64 * K_DIM + koff),
            (lptr3)(smem + ldsbase + u * 8192 + sDst), 16, 0, 0);
    };

#define LOAD_A(Q)                                                               \
    afr[0][0] = *(const v8bf*)(smem + Ab + aRd + (2*(Q)    ) * 2048 + cs0);     \
    afr[0][1] = *(const v8bf*)(smem + Ab + aRd + (2*(Q)    ) * 2048 + cs1);     \
    afr[1][0] = *(const v8bf*)(smem + Ab + aRd + (2*(Q) + 1) * 2048 + cs0);     \
    afr[1][1] = *(const v8bf*)(smem + Ab + aRd + (2*(Q) + 1) * 2048 + cs1);

#define MFMA_Q(Q)                                                               \
    __builtin_amdgcn_s_setprio(1);                                              \
    _Pragma("unroll")                                                           \
    for (int j = 0; j < 2; ++j)                                                 \
        _Pragma("unroll")                                                       \
        for (int nt = 0; nt < 4; ++nt) {                                        \
            acc[2*(Q)+j][nt] = __builtin_amdgcn_mfma_f32_16x16x32_bf16(         \
                afr[j][0], bfr[nt][0], acc[2*(Q)+j][nt], 0, 0, 0);              \
            acc[2*(Q)+j][nt] = __builtin_amdgcn_mfma_f32_16x16x32_bf16(         \
                afr[j][1], bfr[nt][1], acc[2*(Q)+j][nt], 0, 0, 0);              \
        }                                                                       \
    __builtin_amdgcn_s_setprio(0);

    // One K-tile = 4 quadrant-phases; kn = k offset of tile being prefetched.
    auto tile = [&](int BUF, int kn, auto pf_tag) {
        constexpr bool PF = decltype(pf_tag)::value;
        const int Ab = BUF * 32768;
        const int Bb = 65536 + Ab;
        const int Pb = (BUF ^ 1) * 32768;
        v8bf afr[2][2], bfr[4][2];

        // ---- phase 0 : quadrant 0 (mt 0,1); read B.all into regs ----
#pragma unroll
        for (int nt = 0; nt < 4; ++nt) {
            bfr[nt][0] = *(const v8bf*)(smem + Bb + bRd + nt * 2048 + cs0);
            bfr[nt][1] = *(const v8bf*)(smem + Bb + bRd + nt * 2048 + cs1);
        }
        LOAD_A(0)
        if constexpr (PF) { stage1(sB, 65536 + Pb, 0, kn); stage1(sB, 65536 + Pb, 1, kn); }
        __builtin_amdgcn_s_barrier();
        asm volatile("s_waitcnt lgkmcnt(0)" ::: "memory");
        MFMA_Q(0)
        __builtin_amdgcn_s_barrier();

        // ---- phase 1 : quadrant 1 (mt 2,3); W2 retires prev tile's A.u1,u3 ----
        LOAD_A(1)
        if constexpr (PF) {
            stage1(sB, 65536 + Pb, 2, kn); stage1(sB, 65536 + Pb, 3, kn);
            asm volatile("s_waitcnt vmcnt(4)" ::: "memory");
        } else {
            asm volatile("s_waitcnt vmcnt(0)" ::: "memory");   // peeled last tile
        }
        __builtin_amdgcn_s_barrier();
        asm volatile("s_waitcnt lgkmcnt(0)" ::: "memory");
        MFMA_Q(1)
        __builtin_amdgcn_s_barrier();

        // ---- phase 2 : quadrant 2 (mt 4,5) ----
        LOAD_A(2)
        if constexpr (PF) { stage1(sA, Pb, 0, kn); stage1(sA, Pb, 2, kn); }
        __builtin_amdgcn_s_barrier();
        asm volatile("s_waitcnt lgkmcnt(0)" ::: "memory");
        MFMA_Q(2)
        __builtin_amdgcn_s_barrier();

        // ---- phase 3 : quadrant 3 (mt 6,7); W1 readies next tile's ph0 data ----
        LOAD_A(3)
        if constexpr (PF) {
            stage1(sA, Pb, 1, kn); stage1(sA, Pb, 3, kn);
            asm volatile("s_waitcnt vmcnt(2)" ::: "memory");
        }
        __builtin_amdgcn_s_barrier();
        asm volatile("s_waitcnt lgkmcnt(0)" ::: "memory");
        MFMA_Q(3)
        __builtin_amdgcn_s_barrier();
    };

    // prologue: stage tile 0 in consumption order; keep A.u1,u3 in flight
    stage1(sB, 65536, 0, 0); stage1(sB, 65536, 1, 0);
    stage1(sB, 65536, 2, 0); stage1(sB, 65536, 3, 0);
    stage1(sA, 0, 0, 0);     stage1(sA, 0, 2, 0);
    stage1(sA, 0, 1, 0);     stage1(sA, 0, 3, 0);
    asm volatile("s_waitcnt vmcnt(2)" ::: "memory");
    __builtin_amdgcn_s_barrier();

    int kn = 64;
    for (int t = 0; t < NT - 1; ++t) {
        tile(t & 1, kn, std::true_type{});
        kn += 64;
    }
    tile((NT - 1) & 1, 0, std::false_type{});
#undef LOAD_A
#undef MFMA_Q

    // ---- stage c_prev tile (256 rows x 64 f-cols) into padded LDS, coalesced ----
    float* cbuf = (float*)smem;                   // [256][CB_STR] = 68 KB (reuse GEMM LDS)
    const int fbase = n0 >> 2;
#pragma unroll
    for (int i = 0; i < 8; ++i) {
        const int q  = i * 512 + tid;             // 0..4095 float4-chunks
        const int r  = q >> 4;
        const int c4 = (q & 15) << 2;
        *(float4*)&cbuf[r * CB_STR + c4] =
            *(const float4*)&c_prev[(long)(m0 + r) * F_DIM + fbase + c4];
    }
    __syncthreads();

    // ---- fused epilogue (in-register 4x4 gate transpose, LDS-staged c/h) ----
    const int l3 = lane & 3;
    const int fl = (lane >> 2) & 3;
#pragma unroll
    for (int nt = 0; nt < 4; ++nt) {
        const int   gcol = n0 + wni * 64 + nt * 16 + lrow;
        const float bias = bperm[gcol];
#pragma unroll
        for (int mt = 0; mt < 8; ++mt) {
            float a0 = acc[mt][nt][0] + bias;
            float a1 = acc[mt][nt][1] + bias;
            float a2 = acc[mt][nt][2] + bias;
            float a3 = acc[mt][nt][3] + bias;
            // 4x4 transpose across lane quads: stage 1 (xor 1, reg bit 0)
            float s0 = (lane & 1) ? a0 : a1;
            float s1 = (lane & 1) ? a2 : a3;
            float t0 = __shfl_xor(s0, 1, 64);
            float t1 = __shfl_xor(s1, 1, 64);
            if (lane & 1) { a0 = t0; a2 = t1; } else { a1 = t0; a3 = t1; }
            // stage 2 (xor 2, reg bit 1)
            s0 = (lane & 2) ? a0 : a2;
            s1 = (lane & 2) ? a1 : a3;
            t0 = __shfl_xor(s0, 2, 64);
            t1 = __shfl_xor(s1, 2, 64);
            if (lane & 2) { a0 = t0; a1 = t1; } else { a2 = t0; a3 = t1; }
            // a0..a3 = pre-activation i,f,g,o for (local row, local f-col)
            const float iv = sigmoidf_fast(a0);
            const float fv = sigmoidf_fast(a1);
            const float gv = tanhf_fast(a2);
            const float ov = sigmoidf_fast(a3);
            const int lr = wmi * 128 + mt * 16 + quad * 4 + l3;   // 0..255
            const int lc = wni * 16 + nt * 4 + fl;                // 0..63
            const float cp = cbuf[lr * CB_STR + lc];
            const float cv = fv * cp + iv * gv;
            cbuf[lr * CB_STR + lc] = ov * tanhf_fast(cv);         // same-lane cell, no race
        }
    }
    __syncthreads();

    // ---- coalesced h store ----
#pragma unroll
    for (int i = 0; i < 8; ++i) {
        const int q  = i * 512 + tid;
        const int r  = q >> 4;
        const int c4 = (q & 15) << 2;
        *(float4*)&out[(long)(m0 + r) * F_DIM + fbase + c4] =
            *(const float4*)&cbuf[r * CB_STR + c4];
    }
}

// ---------------------------------------------------------------------------
// Inputs (setup_inputs order): behavior, h_prev, c_prev, Wh, Wx, b  (all fp32)
// Output: h (N_ROWS x F_DIM fp32)
// Workspace: A bf16 48 MB | W' bf16 12 MB | b' 16 KB
// ---------------------------------------------------------------------------
extern "C" void kernel_launch(void* const* d_in, const int* in_sizes, int n_in,
                              void* d_out, int out_size, void* d_ws, size_t ws_size,
                              hipStream_t stream) {
    const float* behavior = (const float*)d_in[0];
    const float* h_prev   = (const float*)d_in[1];
    const float* c_prev   = (const float*)d_in[2];
    const float* Wh       = (const float*)d_in[3];
    const float* Wx       = (const float*)d_in[4];
    const float* b        = (const float*)d_in[5];
    float* out = (float*)d_out;

    unsigned short* A  = (unsigned short*)d_ws;
    unsigned short* W  = A + (size_t)N_ROWS * K_DIM;
    float*       bperm = (float*)(W + (size_t)G_DIM * K_DIM);

    hipFuncSetAttribute(reinterpret_cast<const void*>(lstm_gemm),
                        hipFuncAttributeMaxDynamicSharedMemorySize, 131072);

    pack_all<<<N_ROWS + G_DIM, 192, 0, stream>>>(behavior, h_prev, Wh, Wx, b, A, W, bperm);
    lstm_gemm<<<dim3((N_ROWS / 256) * (G_DIM / 256)), 512, 131072, stream>>>(A, W, bperm, c_prev, out);
}

// Round 6
// 423.224 us; speedup vs baseline: 1.0167x; 1.0167x over previous
//
#include <hip/hip_runtime.h>
#include <hip/hip_bf16.h>
#include <stdint.h>
#include <type_traits>

// Problem constants (reference: N=16384, F=1024, B=512)
#define N_ROWS 16384
#define F_DIM  1024
#define B_DIM  512
#define K_DIM  1536   // F + B
#define G_DIM  4096   // 4*F
#define NT     24     // K_DIM / 64 K-tiles
#define CB_STR 68     // padded fp32 stride for epilogue LDS tile

typedef __bf16 v8bf __attribute__((ext_vector_type(8)));
typedef float  v4f  __attribute__((ext_vector_type(4)));

typedef const void __attribute__((address_space(1)))* gptr1;
typedef void       __attribute__((address_space(3)))* lptr3;

__device__ __forceinline__ unsigned short f2bf(float x) {
    union { float f; unsigned int u; } c; c.f = x;
    unsigned int u = c.u;
    return (unsigned short)((u + 0x7FFFu + ((u >> 16) & 1u)) >> 16);  // RNE; inputs finite
}

__device__ __forceinline__ float sigmoidf_fast(float x) {
    return 1.f / (1.f + __expf(-x));
}
__device__ __forceinline__ float tanhf_fast(float x) {
    return 1.f - 2.f / (__expf(2.f * x) + 1.f);   // saturates correctly at +/-1
}

// ---------------------------------------------------------------------------
// Merged pack kernel:
//   blocks [0, N_ROWS)           : A = bf16([h_prev | behavior]) row-major
//   blocks [N_ROWS, N_ROWS+G_DIM): W' = bf16 gate-interleaved [Wh | Wx], b'
// ---------------------------------------------------------------------------
__global__ void pack_all(const float* __restrict__ behavior,
                         const float* __restrict__ h_prev,
                         const float* __restrict__ Wh,
                         const float* __restrict__ Wx,
                         const float* __restrict__ b,
                         unsigned short* __restrict__ A,
                         unsigned short* __restrict__ W,
                         float* __restrict__ bperm) {
    const int blk = blockIdx.x;
    const int col = threadIdx.x * 8;              // 0..1528, never straddles 1024
    const float* src;
    unsigned short* dst;
    if (blk < N_ROWS) {
        src = (col < F_DIM) ? h_prev + (long)blk * F_DIM + col
                            : behavior + (long)blk * B_DIM + (col - F_DIM);
        dst = A + (long)blk * K_DIM + col;
    } else {
        const int gp   = blk - N_ROWS;
        const int gate = gp & 3;
        const int f    = gp >> 2;
        const int g    = gate * F_DIM + f;        // original row in Wh/Wx
        src = (col < F_DIM) ? Wh + (long)g * F_DIM + col
                            : Wx + (long)g * B_DIM + (col - F_DIM);
        dst = W + (long)gp * K_DIM + col;
        if (threadIdx.x == 0) bperm[gp] = b[g];
    }
    float4 lo = *(const float4*)src;
    float4 hi = *(const float4*)(src + 4);
    union { unsigned short u[8]; int4 v; } p;
    p.u[0] = f2bf(lo.x); p.u[1] = f2bf(lo.y); p.u[2] = f2bf(lo.z); p.u[3] = f2bf(lo.w);
    p.u[4] = f2bf(hi.x); p.u[5] = f2bf(hi.y); p.u[6] = f2bf(hi.z); p.u[7] = f2bf(hi.w);
    *(int4*)dst = p.v;
}

// ---------------------------------------------------------------------------
// Fused GEMM (gates = A @ W'^T) + bias + activations + c/h epilogue.
// 256x256 tile, BK=64, 8 waves (2Mx4N), 512 threads.
//
// FREE-RUNNING double-buffer schedule (r5 post-mortem): the clean 2-tile
// double buffer needs exactly ONE barrier per K-tile, not 8:
//  - stage for t+1 goes to buf^1; all reads of buf^1 ended at t-1's
//    end-barrier (WAR safe); reads of buf are unaffected (RAW safe).
//  - vmcnt(0) at tile end waits loads issued a full tile (~2500 cyc)
//    earlier -> already landed, effectively free.
//  - the end barrier publishes buf^1 and fences next tile's staging.
// Inside the tile, waves drift freely: one wave's ds_reads overlap the
// sibling wave's MFMA on the same SIMD (the m114 overlap r0 exploited via
// multi-block residency; here via intra-block drift).
//
// Quadrant decomposition: B (8 b128) read once into regs, held for the
// K-tile; quadrant Q reads A mt{2Q,2Q+1} (4 b128) and does 16 MFMA,
// kh-major so same-acc dependents are 8 instructions apart.
//
// LDS layout (128 KiB, measured conflict-free + 8x128B-coalesced staging):
// A[2 buf][256 rows][128B] at 0, B same at +64KiB; 16B slot s of row r holds
// k-chunk s ^ (r&7); staging lane l covers row l>>3, chunk (l&7)^(l>>3)
// (permutation in global source, LDS dest linear); fragment read offset
// row*128 + (((kh*4+quad) ^ (lrow&7))<<4).
// ---------------------------------------------------------------------------
__global__ __launch_bounds__(512, 2) void lstm_gemm(
    const unsigned short* __restrict__ A,   // [N_ROWS][K_DIM] bf16
    const unsigned short* __restrict__ W,   // [G_DIM][K_DIM]  bf16, interleaved
    const float* __restrict__ bperm,        // [G_DIM]
    const float* __restrict__ c_prev,       // [N_ROWS][F_DIM]
    float* __restrict__ out)                // [N_ROWS][F_DIM]
{
    extern __shared__ char smem[];          // 131072 bytes

    // Plain raster, n fastest (r4-measured: FETCH 254 MB, lowest traffic).
    const int bid = blockIdx.x;                   // 0..1023
    const int n0  = (bid & 15) << 8;              // gate-block * 256
    const int m0  = (bid >> 4) << 8;              // row-block * 256

    const int tid  = threadIdx.x;
    const int lane = tid & 63;
    const int wave = tid >> 6;
    const int wmi  = wave >> 2;                   // 0..1
    const int wni  = wave & 3;                    // 0..3
    const int lrow = lane & 15;
    const int quad = lane >> 4;

    // fragment-read per-lane constants
    const int g7  = lrow & 7;
    const int cs0 = (quad ^ g7) << 4;             // kh0 slot offset (bytes)
    const int cs1 = ((4 + quad) ^ g7) << 4;       // kh1 slot offset
    const int aRd = wmi * 16384 + lrow * 128;     // + buf*32768 + mt*2048 + cs
    const int bRd = wni * 8192  + lrow * 128;     // + 65536 + buf*32768 + nt*2048 + cs

    // staging per-lane source bases: row l>>3, chunk (l&7)^(l>>3)
    const int srow = lane >> 3;
    const int schk = (lane & 7) ^ srow;
    const unsigned short* sA = A + (long)(m0 + wave * 8 + srow) * K_DIM + schk * 8;
    const unsigned short* sB = W + (long)(n0 + wave * 8 + srow) * K_DIM + schk * 8;
    const int sDst = wave * 1024;                 // + matrix base + buf*32768 + u*8192

    v4f acc[8][4] = {};                           // 128 fp32 accum / lane

    // stage one 64-row unit (1 global_load_lds per thread)
    auto stage1 = [&](const unsigned short* src, int ldsbase, int u, int koff) {
        __builtin_amdgcn_global_load_lds(
            (gptr1)(src + (long)u * 64 * K_DIM + koff),
            (lptr3)(smem + ldsbase + u * 8192 + sDst), 16, 0, 0);
    };

    // One K-tile, no internal barriers; kn = k offset of tile being prefetched.
    auto tile = [&](int BUF, int kn, auto pf_tag) {
        constexpr bool PF = decltype(pf_tag)::value;
        const int Ab = BUF * 32768;
        const int Bb = 65536 + Ab;
        const int Pb = (BUF ^ 1) * 32768;
        v8bf afr[2][2], bfr[4][2];

        // issue next tile's staging first (oldest in FIFO, retired at tile end)
        if constexpr (PF) {
#pragma unroll
            for (int u = 0; u < 4; ++u) stage1(sB, 65536 + Pb, u, kn);
#pragma unroll
            for (int u = 0; u < 4; ++u) stage1(sA, Pb, u, kn);
        }

        // B fragments once per K-tile, held in regs
#pragma unroll
        for (int nt = 0; nt < 4; ++nt) {
            bfr[nt][0] = *(const v8bf*)(smem + Bb + bRd + nt * 2048 + cs0);
            bfr[nt][1] = *(const v8bf*)(smem + Bb + bRd + nt * 2048 + cs1);
        }

        // 4 quadrants: 4 A-reads + 16 MFMA each (kh-major, deps 8 apart)
#pragma unroll
        for (int Q = 0; Q < 4; ++Q) {
            afr[0][0] = *(const v8bf*)(smem + Ab + aRd + (2*Q    ) * 2048 + cs0);
            afr[0][1] = *(const v8bf*)(smem + Ab + aRd + (2*Q    ) * 2048 + cs1);
            afr[1][0] = *(const v8bf*)(smem + Ab + aRd + (2*Q + 1) * 2048 + cs0);
            afr[1][1] = *(const v8bf*)(smem + Ab + aRd + (2*Q + 1) * 2048 + cs1);
            __builtin_amdgcn_s_setprio(1);
#pragma unroll
            for (int kh = 0; kh < 2; ++kh)
#pragma unroll
                for (int j = 0; j < 2; ++j)
#pragma unroll
                    for (int nt = 0; nt < 4; ++nt)
                        acc[2*Q + j][nt] = __builtin_amdgcn_mfma_f32_16x16x32_bf16(
                            afr[j][kh], bfr[nt][kh], acc[2*Q + j][nt], 0, 0, 0);
            __builtin_amdgcn_s_setprio(0);
        }

        // retire this tile's prefetch (loads are a full tile old -> cheap),
        // publish buf^1, fence next tile's staging against this tile's reads
        asm volatile("s_waitcnt vmcnt(0)" ::: "memory");
        __builtin_amdgcn_s_barrier();
    };

    // prologue: stage tile 0, wait, publish
#pragma unroll
    for (int u = 0; u < 4; ++u) stage1(sB, 65536, u, 0);
#pragma unroll
    for (int u = 0; u < 4; ++u) stage1(sA, 0, u, 0);
    asm volatile("s_waitcnt vmcnt(0)" ::: "memory");
    __builtin_amdgcn_s_barrier();

    int kn = 64;
    for (int t = 0; t < NT - 1; ++t) {
        tile(t & 1, kn, std::true_type{});
        kn += 64;
    }
    tile((NT - 1) & 1, 0, std::false_type{});

    // ---- stage c_prev tile (256 rows x 64 f-cols) into padded LDS, coalesced ----
    float* cbuf = (float*)smem;                   // [256][CB_STR] = 68 KB (reuse GEMM LDS)
    const int fbase = n0 >> 2;
#pragma unroll
    for (int i = 0; i < 8; ++i) {
        const int q  = i * 512 + tid;             // 0..4095 float4-chunks
        const int r  = q >> 4;
        const int c4 = (q & 15) << 2;
        *(float4*)&cbuf[r * CB_STR + c4] =
            *(const float4*)&c_prev[(long)(m0 + r) * F_DIM + fbase + c4];
    }
    __syncthreads();

    // ---- fused epilogue (in-register 4x4 gate transpose, LDS-staged c/h) ----
    const int l3 = lane & 3;
    const int fl = (lane >> 2) & 3;
#pragma unroll
    for (int nt = 0; nt < 4; ++nt) {
        const int   gcol = n0 + wni * 64 + nt * 16 + lrow;
        const float bias = bperm[gcol];
#pragma unroll
        for (int mt = 0; mt < 8; ++mt) {
            float a0 = acc[mt][nt][0] + bias;
            float a1 = acc[mt][nt][1] + bias;
            float a2 = acc[mt][nt][2] + bias;
            float a3 = acc[mt][nt][3] + bias;
            // 4x4 transpose across lane quads: stage 1 (xor 1, reg bit 0)
            float s0 = (lane & 1) ? a0 : a1;
            float s1 = (lane & 1) ? a2 : a3;
            float t0 = __shfl_xor(s0, 1, 64);
            float t1 = __shfl_xor(s1, 1, 64);
            if (lane & 1) { a0 = t0; a2 = t1; } else { a1 = t0; a3 = t1; }
            // stage 2 (xor 2, reg bit 1)
            s0 = (lane & 2) ? a0 : a2;
            s1 = (lane & 2) ? a1 : a3;
            t0 = __shfl_xor(s0, 2, 64);
            t1 = __shfl_xor(s1, 2, 64);
            if (lane & 2) { a0 = t0; a1 = t1; } else { a2 = t0; a3 = t1; }
            // a0..a3 = pre-activation i,f,g,o for (local row, local f-col)
            const float iv = sigmoidf_fast(a0);
            const float fv = sigmoidf_fast(a1);
            const float gv = tanhf_fast(a2);
            const float ov = sigmoidf_fast(a3);
            const int lr = wmi * 128 + mt * 16 + quad * 4 + l3;   // 0..255
            const int lc = wni * 16 + nt * 4 + fl;                // 0..63
            const float cp = cbuf[lr * CB_STR + lc];
            const float cv = fv * cp + iv * gv;
            cbuf[lr * CB_STR + lc] = ov * tanhf_fast(cv);         // same-lane cell, no race
        }
    }
    __syncthreads();

    // ---- coalesced h store ----
#pragma unroll
    for (int i = 0; i < 8; ++i) {
        const int q  = i * 512 + tid;
        const int r  = q >> 4;
        const int c4 = (q & 15) << 2;
        *(float4*)&out[(long)(m0 + r) * F_DIM + fbase + c4] =
            *(const float4*)&cbuf[r * CB_STR + c4];
    }
}

// ---------------------------------------------------------------------------
// Inputs (setup_inputs order): behavior, h_prev, c_prev, Wh, Wx, b  (all fp32)
// Output: h (N_ROWS x F_DIM fp32)
// Workspace: A bf16 48 MB | W' bf16 12 MB | b' 16 KB
// ---------------------------------------------------------------------------
extern "C" void kernel_launch(void* const* d_in, const int* in_sizes, int n_in,
                              void* d_out, int out_size, void* d_ws, size_t ws_size,
                              hipStream_t stream) {
    const float* behavior = (const float*)d_in[0];
    const float* h_prev   = (const float*)d_in[1];
    const float* c_prev   = (const float*)d_in[2];
    const float* Wh       = (const float*)d_in[3];
    const float* Wx       = (const float*)d_in[4];
    const float* b        = (const float*)d_in[5];
    float* out = (float*)d_out;

    unsigned short* A  = (unsigned short*)d_ws;
    unsigned short* W  = A + (size_t)N_ROWS * K_DIM;
    float*       bperm = (float*)(W + (size_t)G_DIM * K_DIM);

    hipFuncSetAttribute(reinterpret_cast<const void*>(lstm_gemm),
                        hipFuncAttributeMaxDynamicSharedMemorySize, 131072);

    pack_all<<<N_ROWS + G_DIM, 192, 0, stream>>>(behavior, h_prev, Wh, Wx, b, A, W, bperm);
    lstm_gemm<<<dim3((N_ROWS / 256) * (G_DIM / 256)), 512, 131072, stream>>>(A, W, bperm, c_prev, out);
}